// Round 1
// baseline (321.229 us; speedup 1.0000x reference)
//
#include <hip/hip_runtime.h>

// Problem constants (from reference)
#define BATCH   64
#define SEQ     1534
#define C_IN    21
#define DM      516
#define NJ      129      // DM / 4 (float4 chunks per row)
#define KS      8
#define NK      74
#define PADL    21
#define NSPLIT  4        // n-loop split factor (occupancy)
#define JW      12       // j-chunk per block
#define NBJ     11       // ceil(NJ / JW)
#define TSPAN   (12*(JW-1) + 17)             // 149 taps cover jj in [0,JW)
#define TROWS   ((NK + NSPLIT - 1) / NSPLIT) // 19 n-values max per split
#define TABROWS 76       // 24 hour + 7 weekday + 32 day + 13 month rows

typedef float f32x4 __attribute__((ext_vector_type(4)));

// Block = (b, jb, s). Stage x[b, t0:t0+TSPAN, :] into LDS (coalesced,
// zero-padded). NEW vs prev version: also stage (a) the j-slice of all 4
// temporal tables (14.6 KB) and (b) this split's xm rows (6.4 KB) in LDS,
// and use nontemporal stores for the output. This removes ~1 GB of
// redundant L2 gather traffic (5 gathers/output float4) that made the
// kernel L2-BW-bound (~41 us) instead of HBM-write-bound (~33 us), and
// keeps pe (3.17 MB) resident in the 4 MB per-XCD L2.
__global__ __launch_bounds__(256) void embed_kernel(
    const float* __restrict__ x,
    const int*   __restrict__ xm,
    const float* __restrict__ kernels,
    const float* __restrict__ pe,
    const float* __restrict__ hour_tab,
    const float* __restrict__ weekday_tab,
    const float* __restrict__ day_tab,
    const float* __restrict__ month_tab,
    float*       __restrict__ out)
{
    __shared__ float  sk[NK * KS];           // 2.4 KB
    __shared__ float  sx[TSPAN * C_IN];      // 12.5 KB
    __shared__ float4 stab[TABROWS * JW];    // 14.6 KB: [hour|weekday|day|month] j-slices
    __shared__ int4   sxm[TROWS * C_IN];     // 6.4 KB: xm fields 0..3 per (t, ch)

    // decode block: bid = ((b*NBJ + jb)*NSPLIT + s)
    const int bid = blockIdx.x;
    const int s   = bid % NSPLIT;
    const int t1  = bid / NSPLIT;
    const int jb  = t1 % NBJ;
    const int b   = t1 / NBJ;
    const int j0  = jb * JW;
    const int t0  = 12 * j0 - PADL;          // first tap (may be negative)
    const int bSEQ = b * SEQ;
    const int nmax = (NK - 1 - s) / NSPLIT + 1;

    for (int t = threadIdx.x; t < NK * KS; t += 256) sk[t] = kernels[t];

    // Stage x slab: flat floats p in [0, TSPAN*21), global = x[(b*SEQ+t0)*21 + p],
    // zero when t < 0 or t >= SEQ  <=>  p < -t0*21 or p >= (SEQ-t0)*21.
    {
        const int base = (bSEQ + t0) * C_IN;
        const int lo   = -t0 * C_IN;
        const int hi   = (SEQ - t0) * C_IN;
        for (int p = threadIdx.x; p < TSPAN * C_IN; p += 256) {
            float v = 0.0f;
            if (p >= lo && p < hi) v = x[base + p];
            sx[p] = v;
        }
    }

    // Stage temporal tables' j-slice: 76 rows x 12 float4 (zero-padded past NJ).
    {
        const int jlim = NJ - j0;            // valid jj count for this jb
        for (int q = threadIdx.x; q < TABROWS * JW; q += 256) {
            const int r  = q / JW;
            const int jj = q % JW;
            float4 v = make_float4(0.f, 0.f, 0.f, 0.f);
            if (jj < jlim) {
                const float4* src; int rr;
                if (r < 24)      { src = (const float4*)hour_tab;    rr = r; }
                else if (r < 31) { src = (const float4*)weekday_tab; rr = r - 24; }
                else if (r < 63) { src = (const float4*)day_tab;     rr = r - 31; }
                else             { src = (const float4*)month_tab;   rr = r - 63; }
                v = src[rr * NJ + j0 + jj];
            }
            stab[q] = v;
        }
    }

    // Stage xm fields 0..3 for this split's rows: idx = t*C_IN + ch.
    {
        int* sxmi = (int*)sxm;
        for (int p = threadIdx.x; p < nmax * C_IN * 4; p += 256) {
            const int q   = p & 3;
            const int idx = p >> 2;
            const int chh = idx % C_IN;
            const int n   = s + NSPLIT * (idx / C_IN);
            const int i   = n * C_IN + chh;
            int v = 0;
            if (i < SEQ) v = xm[(bSEQ + i) * 5 + q];   // guard fin-row ch>0 (i>=SEQ)
            sxmi[p] = v;
        }
    }
    __syncthreads();

    const int ch = threadIdx.x / JW;
    const int jj = threadIdx.x % JW;
    const int j  = j0 + jj;
    if (ch >= C_IN || j >= NJ) return;

    // 17 taps for d in [4j, 4j+4): t = 12j - 21 + u  ->  LDS (12jj+u)*21 + ch
    float w[17];
#pragma unroll
    for (int u = 0; u < 17; ++u) w[u] = sx[(12 * jj + u) * C_IN + ch];

    const float4* pe4 = (const float4*)pe;
    float4*       o4  = (float4*)out;

    for (int t = 0; t < nmax; ++t) {
        const int n = s + NSPLIT * t;
        if (n == NK - 1 && ch != 0) continue;   // fin row (i=1533) only for ch==0
        const int i = n * C_IN + ch;

        float acc[4];
#pragma unroll
        for (int dd = 0; dd < 4; ++dd) {
            float a = 0.0f;
#pragma unroll
            for (int k = 0; k < KS; ++k) a += w[3 * dd + k] * sk[n * KS + k];
            acc[dd] = a;
        }

        // xm fields: .x=month .y=day .z=weekday .w=hour (matches xr[0..3])
        const int4 xi = sxm[t * C_IN + ch];

        const float4 p  = pe4[i * NJ + j];               // L2-resident (3.17 MB)
        const float4 th = stab[ xi.w        * JW + jj];  // hour
        const float4 tw = stab[(24 + xi.z)  * JW + jj];  // weekday
        const float4 td = stab[(31 + xi.y)  * JW + jj];  // day
        const float4 tm = stab[(63 + xi.x)  * JW + jj];  // month

        f32x4 o;
        o.x = acc[0] + p.x + th.x + tw.x + td.x + tm.x;
        o.y = acc[1] + p.y + th.y + tw.y + td.y + tm.y;
        o.z = acc[2] + p.z + th.z + tw.z + td.z + tm.z;
        o.w = acc[3] + p.w + th.w + tw.w + td.w + tm.w;

        // Streaming output: bypass/deprioritize L2 so pe stays resident.
        __builtin_nontemporal_store(o, (f32x4*)&o4[(bSEQ + i) * NJ + j]);
    }
}

extern "C" void kernel_launch(void* const* d_in, const int* in_sizes, int n_in,
                              void* d_out, int out_size, void* d_ws, size_t ws_size,
                              hipStream_t stream) {
    const float* x        = (const float*)d_in[0];
    const int*   x_mark   = (const int*)  d_in[1];
    const float* kernels  = (const float*)d_in[2];
    const float* pe       = (const float*)d_in[3];
    const float* hour_tab = (const float*)d_in[4];
    const float* wday_tab = (const float*)d_in[5];
    const float* day_tab  = (const float*)d_in[6];
    const float* mon_tab  = (const float*)d_in[7];
    float*       out      = (float*)d_out;

    const int blocks = BATCH * NBJ * NSPLIT;   // 64*11*4 = 2816
    embed_kernel<<<blocks, 256, 0, stream>>>(
        x, x_mark, kernels, pe, hour_tab, wday_tab, day_tab, mon_tab, out);
}

// Round 2
// 283.173 us; speedup vs baseline: 1.1344x; 1.1344x over previous
//
#include <hip/hip_runtime.h>

// Problem constants (from reference)
#define BATCH   64
#define SEQ     1534
#define C_IN    21
#define DM      516
#define NJ      129      // DM / 4 (float4 chunks per row)
#define KS      8
#define NK      74
#define PADL    21
#define NSPLIT  4        // n-loop split factor (occupancy)
#define JW      12       // j-chunk per block
#define NBJ     11       // ceil(NJ / JW)
#define TSPAN   (12*(JW-1) + 17)   // 149 taps cover jj in [0,JW)

// Block = (b, jb, s). Stage x[b, t0:t0+TSPAN, :] into LDS (coalesced,
// zero-padded), then thread (ch, jj) reads its 17 taps from LDS into
// registers and emits rows i = n*21+ch for n = s, s+NSPLIT, ...
//
// NOTE (round-1 post-mortem): this version runs at ~41 us, 95% of the
// 38.7 us HBM traffic floor (FETCH 23.5 MB + WRITE 220 MB at 6.3 TB/s).
// Do NOT: (a) stage the temporal tables in LDS (36 KB LDS halves
// occupancy; wave-level table reads are already 192 B-coalesced and
// cache-resident — FETCH is only 23 MB); (b) use nontemporal stores
// (192 B/wave-segment partial-line writes need L2 write-back merging
// across jb-blocks; `nt` bypasses it -> HBM RMW, BW drops to 22%).
// That experiment measured 140 us (3.4x regression).
__global__ __launch_bounds__(256) void embed_kernel(
    const float* __restrict__ x,
    const int*   __restrict__ xm,
    const float* __restrict__ kernels,
    const float* __restrict__ pe,
    const float* __restrict__ hour_tab,
    const float* __restrict__ weekday_tab,
    const float* __restrict__ day_tab,
    const float* __restrict__ month_tab,
    float*       __restrict__ out)
{
    __shared__ float sk[NK * KS];        // 592 floats
    __shared__ float sx[TSPAN * C_IN];   // 3129 floats = 12.5 KB

    // decode block: bid = ((b*NBJ + jb)*NSPLIT + s)
    const int bid = blockIdx.x;
    const int s   = bid % NSPLIT;
    const int t1  = bid / NSPLIT;
    const int jb  = t1 % NBJ;
    const int b   = t1 / NBJ;
    const int j0  = jb * JW;
    const int t0  = 12 * j0 - PADL;      // first tap (may be negative)

    for (int t = threadIdx.x; t < NK * KS; t += 256) sk[t] = kernels[t];

    // Stage x slab: flat floats p in [0, TSPAN*21), global = x[(b*SEQ+t0)*21 + p],
    // zero when t < 0 or t >= SEQ  <=>  p < -t0*21 or p >= (SEQ-t0)*21.
    {
        const int base = (b * SEQ + t0) * C_IN;
        const int lo   = -t0 * C_IN;
        const int hi   = (SEQ - t0) * C_IN;
        for (int p = threadIdx.x; p < TSPAN * C_IN; p += 256) {
            float v = 0.0f;
            if (p >= lo && p < hi) v = x[base + p];
            sx[p] = v;
        }
    }
    __syncthreads();

    const int ch = threadIdx.x / JW;
    const int jj = threadIdx.x % JW;
    const int j  = j0 + jj;
    if (ch >= C_IN || j >= NJ) return;

    // 17 taps for d in [4j, 4j+4): t = 12j - 21 + u  ->  LDS (12jj+u)*21 + ch
    float w[17];
#pragma unroll
    for (int u = 0; u < 17; ++u) w[u] = sx[(12 * jj + u) * C_IN + ch];

    const float4* pe4 = (const float4*)pe;
    const float4* h4  = (const float4*)hour_tab;
    const float4* wd4 = (const float4*)weekday_tab;
    const float4* dy4 = (const float4*)day_tab;
    const float4* mo4 = (const float4*)month_tab;
    float4*       o4  = (float4*)out;

    const int bSEQ = b * SEQ;

    for (int n = s; n < NK; n += NSPLIT) {
        if (n == NK - 1 && ch != 0) continue;   // fin row (i=1533) only for ch==0
        const int i = n * C_IN + ch;

        float acc[4];
#pragma unroll
        for (int dd = 0; dd < 4; ++dd) {
            float a = 0.0f;
#pragma unroll
            for (int k = 0; k < KS; ++k) a += w[3 * dd + k] * sk[n * KS + k];
            acc[dd] = a;
        }

        const int* xr = xm + (bSEQ + i) * 5;
        const int hi = xr[3], wi = xr[2], di = xr[1], mi = xr[0];

        const float4 p  = pe4[i * NJ + j];
        const float4 th = h4 [hi * NJ + j];
        const float4 tw = wd4[wi * NJ + j];
        const float4 td = dy4[di * NJ + j];
        const float4 tm = mo4[mi * NJ + j];

        float4 o;
        o.x = acc[0] + p.x + th.x + tw.x + td.x + tm.x;
        o.y = acc[1] + p.y + th.y + tw.y + td.y + tm.y;
        o.z = acc[2] + p.z + th.z + tw.z + td.z + tm.z;
        o.w = acc[3] + p.w + th.w + tw.w + td.w + tm.w;

        o4[(bSEQ + i) * NJ + j] = o;
    }
}

extern "C" void kernel_launch(void* const* d_in, const int* in_sizes, int n_in,
                              void* d_out, int out_size, void* d_ws, size_t ws_size,
                              hipStream_t stream) {
    const float* x        = (const float*)d_in[0];
    const int*   x_mark   = (const int*)  d_in[1];
    const float* kernels  = (const float*)d_in[2];
    const float* pe       = (const float*)d_in[3];
    const float* hour_tab = (const float*)d_in[4];
    const float* wday_tab = (const float*)d_in[5];
    const float* day_tab  = (const float*)d_in[6];
    const float* mon_tab  = (const float*)d_in[7];
    float*       out      = (float*)d_out;

    const int blocks = BATCH * NBJ * NSPLIT;   // 64*11*4 = 2816
    embed_kernel<<<blocks, 256, 0, stream>>>(
        x, x_mark, kernels, pe, hour_tab, wday_tab, day_tab, mon_tab, out);
}